// Round 4
// baseline (4467.834 us; speedup 1.0000x reference)
//
#include <hip/hip_runtime.h>

// ---------------------------------------------------------------------------
// 2-layer LSTM (H=51) + Linear(51,1), B=1024, T=1024, fp32.
// Design (R4): one block per batch element, 256 threads (4 waves).
//   - lane g (<204) owns gate row g; weights held as float2 pairs in VGPRs
//     (78 f2 = 156 regs). __launch_bounds__(256,1) gives the allocator up to
//     512 VGPRs -> NO scratch spill (R3 spilled: 18.7 GB HBM traffic/dispatch
//     at VGPR_Count=128; that was the 4 ms bottleneck).
//   - dot products use packed fp32: acc2 = w2*h2 + acc2 -> v_pk_fma_f32
//     (2 MACs/instr; the quoted 157 TF fp32 needs packed math).
//   - h1/h2 broadcast via LDS ds_read (same-address broadcast, conflict-free).
//   - gates via two LDS buffers (A: layer1, B: layer2) -> only 3 barriers/step.
//   - fast activations: __expf + v_rcp_f32 (error ~1e-6, budget 1.66e-3).
// ---------------------------------------------------------------------------

#define H    51
#define NG   204      // 4*H
#define TLEN 1024
#define BATCH 1024

typedef __attribute__((ext_vector_type(2))) float f2;

__device__ __forceinline__ float frcp(float x) { return __builtin_amdgcn_rcpf(x); }

// sigmoid-family gate: act(x) = am * rcp(1 + exp(sm*x)) + bm
__device__ __forceinline__ float gate_act(float pre, float sm, float am, float bm) {
    return am * frcp(1.0f + __expf(sm * pre)) + bm;
}
// tanh(x) = 1 - 2/(exp(2x)+1)
__device__ __forceinline__ float ftanh(float x) {
    return 1.0f - 2.0f * frcp(__expf(2.0f * x) + 1.0f);
}

// 51-dot as 26 packed-fp32 FMAs over float2 pairs, 2 accumulator chains.
#define DOT51PK(W, HP)                                                       \
    {                                                                        \
        _Pragma("unroll")                                                    \
        for (int i = 0; i < 13; ++i) {                                       \
            acc0 = (W)[2 * i]     * (HP)[2 * i]     + acc0;                  \
            acc1 = (W)[2 * i + 1] * (HP)[2 * i + 1] + acc1;                  \
        }                                                                    \
    }

__global__ __launch_bounds__(256, 1)
void lstm2_kernel(const float* __restrict__ input,
                  const float* __restrict__ W_ih1, const float* __restrict__ W_hh1,
                  const float* __restrict__ b_ih1, const float* __restrict__ b_hh1,
                  const float* __restrict__ W_ih2, const float* __restrict__ W_hh2,
                  const float* __restrict__ b_ih2, const float* __restrict__ b_hh2,
                  const float* __restrict__ W_lin, const float* __restrict__ b_lin,
                  float* __restrict__ out)
{
    const int b   = blockIdx.x;
    const int tid = threadIdx.x;
    const int g   = tid < NG ? tid : NG - 1;

    __shared__ __align__(16) float sh_h1[64];   // h1[0..50]; [51..63] stay 0
    __shared__ __align__(16) float sh_h2[64];   // h2[0..50]; [51..63] stay 0
    __shared__ float sh_gA[NG];                 // layer-1 gates
    __shared__ float sh_gB[NG];                 // layer-2 gates

    if (tid < 64) { sh_h1[tid] = 0.0f; sh_h2[tid] = 0.0f; }

    // persistent per-lane weight rows as float2 pairs (VGPRs, loaded once)
    f2 w1[26], wi2[26], wh2[26];
#pragma unroll
    for (int k = 0; k < 25; ++k) {
        w1[k]  = f2{W_hh1[g * H + 2 * k], W_hh1[g * H + 2 * k + 1]};
        wi2[k] = f2{W_ih2[g * H + 2 * k], W_ih2[g * H + 2 * k + 1]};
        wh2[k] = f2{W_hh2[g * H + 2 * k], W_hh2[g * H + 2 * k + 1]};
    }
    w1[25]  = f2{W_hh1[g * H + 50], 0.0f};      // pair (w[50], 0); h[51]==0
    wi2[25] = f2{W_ih2[g * H + 50], 0.0f};
    wh2[25] = f2{W_hh2[g * H + 50], 0.0f};

    const float wx  = W_ih1[g];
    const float bb1 = b_ih1[g] + b_hh1[g];
    const float bb2 = b_ih2[g] + b_hh2[g];

    // gate activation: i,f,o -> sigmoid ; g-rows (102..152) -> tanh (branchless)
    const bool tg = (g >= 2 * H) && (g < 3 * H);
    const float sm = tg ? -2.0f : -1.0f;
    const float am = tg ?  2.0f :  1.0f;
    const float bm = tg ? -1.0f :  0.0f;

    const float wl   = (tid < H) ? W_lin[tid] : 0.0f;
    const float blin = b_lin[0];

    float c1 = 0.0f, c2 = 0.0f;

    const float* xrow = input + (size_t)b * TLEN;
    float*       orow = out   + (size_t)b * TLEN;

    const f2* h1p = (const f2*)sh_h1;
    const f2* h2p = (const f2*)sh_h2;

    __syncthreads();                              // h zeros visible

    for (int t = 0; t < TLEN; ++t) {
        const float x = xrow[t];                  // uniform load, consumed late

        // ---------------- layer 1 gates: needs h1_prev ----------------
        f2 acc0 = f2{0.0f, 0.0f}, acc1 = f2{0.0f, 0.0f};
        DOT51PK(w1, h1p);
        {
            const float pre = (acc0.x + acc0.y) + (acc1.x + acc1.y)
                            + bb1 + wx * x;
            if (tid < NG) sh_gA[tid] = gate_act(pre, sm, am, bm);
        }
        __syncthreads();                                        // B1

        // ---------------- layer 1 elementwise (lanes 0..50, wave 0) ---
        if (tid < H) {
            const float ig = sh_gA[tid];
            const float fg = sh_gA[H + tid];
            const float gg = sh_gA[2 * H + tid];
            const float og = sh_gA[3 * H + tid];
            c1 = fg * c1 + ig * gg;
            sh_h1[tid] = og * ftanh(c1);                        // h1_new
        }
        __syncthreads();                                        // B2

        // ---------------- layer 2 gates: h1_new and h2_prev -----------
        acc0 = f2{0.0f, 0.0f}; acc1 = f2{0.0f, 0.0f};
        DOT51PK(wi2, h1p);
        DOT51PK(wh2, h2p);
        {
            const float pre = (acc0.x + acc0.y) + (acc1.x + acc1.y) + bb2;
            if (tid < NG) sh_gB[tid] = gate_act(pre, sm, am, bm);
        }
        __syncthreads();                                        // B3

        // ---------------- layer 2 elementwise + linear ----------------
        float yp = 0.0f;
        if (tid < H) {
            const float ig = sh_gB[tid];
            const float fg = sh_gB[H + tid];
            const float gg = sh_gB[2 * H + tid];
            const float og = sh_gB[3 * H + tid];
            c2 = fg * c2 + ig * gg;
            const float h2n = og * ftanh(c2);
            sh_h2[tid] = h2n;                                   // h2_new
            yp = wl * h2n;
        }
        if (tid < 64) {                          // wave 0: reduce 51 terms
            yp += __shfl_down(yp, 32);
            yp += __shfl_down(yp, 16);
            yp += __shfl_down(yp, 8);
            yp += __shfl_down(yp, 4);
            yp += __shfl_down(yp, 2);
            yp += __shfl_down(yp, 1);
            if (tid == 0) orow[t] = yp + blin;
        }
        // no B4: next write of sh_h2/sh_gB is behind B2(t+1)/B3(t+1);
        // next write of sh_gA (gates1 store, t+1) is behind B3(t) and only
        // read again after B1(t+1).  All last-read -> next-write pairs are
        // barrier-separated.
    }
}

extern "C" void kernel_launch(void* const* d_in, const int* in_sizes, int n_in,
                              void* d_out, int out_size, void* d_ws, size_t ws_size,
                              hipStream_t stream)
{
    const float* input = (const float*)d_in[0];
    const float* W_ih1 = (const float*)d_in[1];
    const float* W_hh1 = (const float*)d_in[2];
    const float* b_ih1 = (const float*)d_in[3];
    const float* b_hh1 = (const float*)d_in[4];
    const float* W_ih2 = (const float*)d_in[5];
    const float* W_hh2 = (const float*)d_in[6];
    const float* b_ih2 = (const float*)d_in[7];
    const float* b_hh2 = (const float*)d_in[8];
    const float* W_lin = (const float*)d_in[9];
    const float* b_lin = (const float*)d_in[10];

    float* out = (float*)d_out;

    hipLaunchKernelGGL(lstm2_kernel, dim3(BATCH), dim3(256), 0, stream,
                       input, W_ih1, W_hh1, b_ih1, b_hh1,
                       W_ih2, W_hh2, b_ih2, b_hh2, W_lin, b_lin,
                       out);
}

// Round 5
// 3631.982 us; speedup vs baseline: 1.2301x; 1.2301x over previous
//
#include <hip/hip_runtime.h>

// ---------------------------------------------------------------------------
// 2-layer LSTM (H=51) + Linear(51,1), B=1024, T=1024, fp32.
// Design (R5): one block per batch element, 256 threads (4 waves).
//   - lane g (<204) owns gate row g; weights held as float2 pairs and PINNED
//     into VGPRs via opaque asm ("+v") so the allocator cannot rematerialize
//     per-step global reloads. R3/R4 both ran at VGPR_Count=128/140 < the 156
//     needed -> ~131 GB of L2 weight re-reads = the whole 4 ms runtime.
//   - __launch_bounds__(256,2): 256-VGPR budget (fits 156 pinned + working).
//   - dot products: packed fp32 v_pk_fma_f32 over float2 pairs.
//   - h1/h2 broadcast via LDS (same-address broadcast, conflict-free).
//   - gates via two LDS buffers; 3 barriers/step.
//   - fast activations: __expf + v_rcp_f32 (err ~1e-6, budget 1.66e-3).
// ---------------------------------------------------------------------------

#define H    51
#define NG   204      // 4*H
#define TLEN 1024
#define BATCH 1024

typedef __attribute__((ext_vector_type(2))) float f2;

__device__ __forceinline__ float frcp(float x) { return __builtin_amdgcn_rcpf(x); }

// sigmoid-family gate: act(x) = am * rcp(1 + exp(sm*x)) + bm
__device__ __forceinline__ float gate_act(float pre, float sm, float am, float bm) {
    return am * frcp(1.0f + __expf(sm * pre)) + bm;
}
// tanh(x) = 1 - 2/(exp(2x)+1)
__device__ __forceinline__ float ftanh(float x) {
    return 1.0f - 2.0f * frcp(__expf(2.0f * x) + 1.0f);
}

// 51-dot as 26 packed-fp32 FMAs over float2 pairs, 2 accumulator chains.
#define DOT51PK(W, HP)                                                       \
    {                                                                        \
        _Pragma("unroll")                                                    \
        for (int i = 0; i < 13; ++i) {                                       \
            acc0 = (W)[2 * i]     * (HP)[2 * i]     + acc0;                  \
            acc1 = (W)[2 * i + 1] * (HP)[2 * i + 1] + acc1;                  \
        }                                                                    \
    }

__global__ __launch_bounds__(256, 2)
void lstm2_kernel(const float* __restrict__ input,
                  const float* __restrict__ W_ih1, const float* __restrict__ W_hh1,
                  const float* __restrict__ b_ih1, const float* __restrict__ b_hh1,
                  const float* __restrict__ W_ih2, const float* __restrict__ W_hh2,
                  const float* __restrict__ b_ih2, const float* __restrict__ b_hh2,
                  const float* __restrict__ W_lin, const float* __restrict__ b_lin,
                  float* __restrict__ out)
{
    const int b   = blockIdx.x;
    const int tid = threadIdx.x;
    const int g   = tid < NG ? tid : NG - 1;

    __shared__ __align__(16) float sh_h1[64];   // h1[0..50]; [51..63] stay 0
    __shared__ __align__(16) float sh_h2[64];   // h2[0..50]; [51..63] stay 0
    __shared__ float sh_gA[NG];                 // layer-1 gates
    __shared__ float sh_gB[NG];                 // layer-2 gates

    if (tid < 64) { sh_h1[tid] = 0.0f; sh_h2[tid] = 0.0f; }

    // persistent per-lane weight rows as float2 pairs (VGPRs, loaded once)
    f2 w1[26], wi2[26], wh2[26];
#pragma unroll
    for (int k = 0; k < 25; ++k) {
        w1[k]  = f2{W_hh1[g * H + 2 * k], W_hh1[g * H + 2 * k + 1]};
        wi2[k] = f2{W_ih2[g * H + 2 * k], W_ih2[g * H + 2 * k + 1]};
        wh2[k] = f2{W_hh2[g * H + 2 * k], W_hh2[g * H + 2 * k + 1]};
    }
    w1[25]  = f2{W_hh1[g * H + 50], 0.0f};      // pair (w[50], 0); h[51]==0
    wi2[25] = f2{W_ih2[g * H + 50], 0.0f};
    wh2[25] = f2{W_hh2[g * H + 50], 0.0f};

    // PIN the weights in VGPRs: opaque asm makes them non-rematerializable,
    // so the allocator cannot replace them with per-step global reloads.
#pragma unroll
    for (int k = 0; k < 26; ++k) {
        asm volatile("" : "+v"(w1[k]), "+v"(wi2[k]), "+v"(wh2[k]));
    }

    const float wx  = W_ih1[g];
    const float bb1 = b_ih1[g] + b_hh1[g];
    const float bb2 = b_ih2[g] + b_hh2[g];

    // gate activation: i,f,o -> sigmoid ; g-rows (102..152) -> tanh (branchless)
    const bool tg = (g >= 2 * H) && (g < 3 * H);
    const float sm = tg ? -2.0f : -1.0f;
    const float am = tg ?  2.0f :  1.0f;
    const float bm = tg ? -1.0f :  0.0f;

    const float wl   = (tid < H) ? W_lin[tid] : 0.0f;
    const float blin = b_lin[0];

    float c1 = 0.0f, c2 = 0.0f;

    const float* xrow = input + (size_t)b * TLEN;
    float*       orow = out   + (size_t)b * TLEN;

    const f2* h1p = (const f2*)sh_h1;
    const f2* h2p = (const f2*)sh_h2;

    __syncthreads();                              // h zeros visible

    for (int t = 0; t < TLEN; ++t) {
        const float x = xrow[t];                  // uniform (scalar) load

        // ---------------- layer 1 gates: needs h1_prev ----------------
        f2 acc0 = f2{0.0f, 0.0f}, acc1 = f2{0.0f, 0.0f};
        DOT51PK(w1, h1p);
        {
            const float pre = (acc0.x + acc0.y) + (acc1.x + acc1.y)
                            + bb1 + wx * x;
            if (tid < NG) sh_gA[tid] = gate_act(pre, sm, am, bm);
        }
        __syncthreads();                                        // B1

        // ---------------- layer 1 elementwise (lanes 0..50, wave 0) ---
        if (tid < H) {
            const float ig = sh_gA[tid];
            const float fg = sh_gA[H + tid];
            const float gg = sh_gA[2 * H + tid];
            const float og = sh_gA[3 * H + tid];
            c1 = fg * c1 + ig * gg;
            sh_h1[tid] = og * ftanh(c1);                        // h1_new
        }
        __syncthreads();                                        // B2

        // ---------------- layer 2 gates: h1_new and h2_prev -----------
        acc0 = f2{0.0f, 0.0f}; acc1 = f2{0.0f, 0.0f};
        DOT51PK(wi2, h1p);
        DOT51PK(wh2, h2p);
        {
            const float pre = (acc0.x + acc0.y) + (acc1.x + acc1.y) + bb2;
            if (tid < NG) sh_gB[tid] = gate_act(pre, sm, am, bm);
        }
        __syncthreads();                                        // B3

        // ---------------- layer 2 elementwise + linear ----------------
        float yp = 0.0f;
        if (tid < H) {
            const float ig = sh_gB[tid];
            const float fg = sh_gB[H + tid];
            const float gg = sh_gB[2 * H + tid];
            const float og = sh_gB[3 * H + tid];
            c2 = fg * c2 + ig * gg;
            const float h2n = og * ftanh(c2);
            sh_h2[tid] = h2n;                                   // h2_new
            yp = wl * h2n;
        }
        if (tid < 64) {                          // wave 0: reduce 51 terms
            yp += __shfl_down(yp, 32);
            yp += __shfl_down(yp, 16);
            yp += __shfl_down(yp, 8);
            yp += __shfl_down(yp, 4);
            yp += __shfl_down(yp, 2);
            yp += __shfl_down(yp, 1);
            if (tid == 0) orow[t] = yp + blin;
        }
        // no B4: every last-read -> next-write pair on sh_h2/sh_gA/sh_gB is
        // separated by at least one of B1(t+1)/B2(t+1)/B3(t+1).
    }
}

extern "C" void kernel_launch(void* const* d_in, const int* in_sizes, int n_in,
                              void* d_out, int out_size, void* d_ws, size_t ws_size,
                              hipStream_t stream)
{
    const float* input = (const float*)d_in[0];
    const float* W_ih1 = (const float*)d_in[1];
    const float* W_hh1 = (const float*)d_in[2];
    const float* b_ih1 = (const float*)d_in[3];
    const float* b_hh1 = (const float*)d_in[4];
    const float* W_ih2 = (const float*)d_in[5];
    const float* W_hh2 = (const float*)d_in[6];
    const float* b_ih2 = (const float*)d_in[7];
    const float* b_hh2 = (const float*)d_in[8];
    const float* W_lin = (const float*)d_in[9];
    const float* b_lin = (const float*)d_in[10];

    float* out = (float*)d_out;

    hipLaunchKernelGGL(lstm2_kernel, dim3(BATCH), dim3(256), 0, stream,
                       input, W_ih1, W_hh1, b_ih1, b_hh1,
                       W_ih2, W_hh2, b_ih2, b_hh2, W_lin, b_lin,
                       out);
}

// Round 6
// 3541.834 us; speedup vs baseline: 1.2614x; 1.0255x over previous
//
#include <hip/hip_runtime.h>

// ---------------------------------------------------------------------------
// 2-layer LSTM (H=51) + Linear(51,1), B=1024, T=1024, fp32.
// Design (R6 = R5 + amdgpu_waves_per_eu(2,2)): one block/batch, 256 threads.
//   - R3..R5 all spilled the 156 per-lane weight regs to scratch
//     (VGPR_Count 128/140; ~131 GB L2 refill traffic = the whole ~4 ms).
//     launch_bounds' 2nd arg only CAPS VGPRs; the scheduler still TARGETED
//     4 waves/EU (=128 regs) and spilled to reach it.
//   - amdgpu_waves_per_eu(2,2) pins the occupancy target itself at 2 waves/EU
//     -> pressure limit 256 VGPRs -> the ~216 live regs fit, no spill.
//     2 blocks/CU (8 waves/CU) still co-resident.
//   - lane g (<204) owns gate row g; weights as float2 pairs, "+v"-pinned.
//   - dot products: packed fp32 v_pk_fma_f32 over float2 pairs.
//   - h1/h2 broadcast via LDS (same-address broadcast, conflict-free).
//   - gates via two LDS buffers; 3 barriers/step.
//   - fast activations: __expf + v_rcp_f32 (err ~1e-6, budget 1.66e-3).
// ---------------------------------------------------------------------------

#define H    51
#define NG   204      // 4*H
#define TLEN 1024
#define BATCH 1024

typedef __attribute__((ext_vector_type(2))) float f2;

__device__ __forceinline__ float frcp(float x) { return __builtin_amdgcn_rcpf(x); }

// sigmoid-family gate: act(x) = am * rcp(1 + exp(sm*x)) + bm
__device__ __forceinline__ float gate_act(float pre, float sm, float am, float bm) {
    return am * frcp(1.0f + __expf(sm * pre)) + bm;
}
// tanh(x) = 1 - 2/(exp(2x)+1)
__device__ __forceinline__ float ftanh(float x) {
    return 1.0f - 2.0f * frcp(__expf(2.0f * x) + 1.0f);
}

// 51-dot as 26 packed-fp32 FMAs over float2 pairs, 2 accumulator chains.
#define DOT51PK(W, HP)                                                       \
    {                                                                        \
        _Pragma("unroll")                                                    \
        for (int i = 0; i < 13; ++i) {                                       \
            acc0 = (W)[2 * i]     * (HP)[2 * i]     + acc0;                  \
            acc1 = (W)[2 * i + 1] * (HP)[2 * i + 1] + acc1;                  \
        }                                                                    \
    }

__global__
__attribute__((amdgpu_flat_work_group_size(256, 256), amdgpu_waves_per_eu(2, 2)))
void lstm2_kernel(const float* __restrict__ input,
                  const float* __restrict__ W_ih1, const float* __restrict__ W_hh1,
                  const float* __restrict__ b_ih1, const float* __restrict__ b_hh1,
                  const float* __restrict__ W_ih2, const float* __restrict__ W_hh2,
                  const float* __restrict__ b_ih2, const float* __restrict__ b_hh2,
                  const float* __restrict__ W_lin, const float* __restrict__ b_lin,
                  float* __restrict__ out)
{
    const int b   = blockIdx.x;
    const int tid = threadIdx.x;
    const int g   = tid < NG ? tid : NG - 1;

    __shared__ __align__(16) float sh_h1[64];   // h1[0..50]; [51..63] stay 0
    __shared__ __align__(16) float sh_h2[64];   // h2[0..50]; [51..63] stay 0
    __shared__ float sh_gA[NG];                 // layer-1 gates
    __shared__ float sh_gB[NG];                 // layer-2 gates

    if (tid < 64) { sh_h1[tid] = 0.0f; sh_h2[tid] = 0.0f; }

    // persistent per-lane weight rows as float2 pairs (VGPRs, loaded once)
    f2 w1[26], wi2[26], wh2[26];
#pragma unroll
    for (int k = 0; k < 25; ++k) {
        w1[k]  = f2{W_hh1[g * H + 2 * k], W_hh1[g * H + 2 * k + 1]};
        wi2[k] = f2{W_ih2[g * H + 2 * k], W_ih2[g * H + 2 * k + 1]};
        wh2[k] = f2{W_hh2[g * H + 2 * k], W_hh2[g * H + 2 * k + 1]};
    }
    w1[25]  = f2{W_hh1[g * H + 50], 0.0f};      // pair (w[50], 0); h[51]==0
    wi2[25] = f2{W_ih2[g * H + 50], 0.0f};
    wh2[25] = f2{W_hh2[g * H + 50], 0.0f};

    // PIN the weights in VGPRs: opaque asm makes them non-rematerializable.
#pragma unroll
    for (int k = 0; k < 26; ++k) {
        asm volatile("" : "+v"(w1[k]), "+v"(wi2[k]), "+v"(wh2[k]));
    }

    const float wx  = W_ih1[g];
    const float bb1 = b_ih1[g] + b_hh1[g];
    const float bb2 = b_ih2[g] + b_hh2[g];

    // gate activation: i,f,o -> sigmoid ; g-rows (102..152) -> tanh (branchless)
    const bool tg = (g >= 2 * H) && (g < 3 * H);
    const float sm = tg ? -2.0f : -1.0f;
    const float am = tg ?  2.0f :  1.0f;
    const float bm = tg ? -1.0f :  0.0f;

    const float wl   = (tid < H) ? W_lin[tid] : 0.0f;
    const float blin = b_lin[0];

    float c1 = 0.0f, c2 = 0.0f;

    const float* xrow = input + (size_t)b * TLEN;
    float*       orow = out   + (size_t)b * TLEN;

    const f2* h1p = (const f2*)sh_h1;
    const f2* h2p = (const f2*)sh_h2;

    __syncthreads();                              // h zeros visible

    for (int t = 0; t < TLEN; ++t) {
        const float x = xrow[t];                  // uniform (scalar) load

        // ---------------- layer 1 gates: needs h1_prev ----------------
        f2 acc0 = f2{0.0f, 0.0f}, acc1 = f2{0.0f, 0.0f};
        DOT51PK(w1, h1p);
        {
            const float pre = (acc0.x + acc0.y) + (acc1.x + acc1.y)
                            + bb1 + wx * x;
            if (tid < NG) sh_gA[tid] = gate_act(pre, sm, am, bm);
        }
        __syncthreads();                                        // B1

        // ---------------- layer 1 elementwise (lanes 0..50, wave 0) ---
        if (tid < H) {
            const float ig = sh_gA[tid];
            const float fg = sh_gA[H + tid];
            const float gg = sh_gA[2 * H + tid];
            const float og = sh_gA[3 * H + tid];
            c1 = fg * c1 + ig * gg;
            sh_h1[tid] = og * ftanh(c1);                        // h1_new
        }
        __syncthreads();                                        // B2

        // ---------------- layer 2 gates: h1_new and h2_prev -----------
        acc0 = f2{0.0f, 0.0f}; acc1 = f2{0.0f, 0.0f};
        DOT51PK(wi2, h1p);
        DOT51PK(wh2, h2p);
        {
            const float pre = (acc0.x + acc0.y) + (acc1.x + acc1.y) + bb2;
            if (tid < NG) sh_gB[tid] = gate_act(pre, sm, am, bm);
        }
        __syncthreads();                                        // B3

        // ---------------- layer 2 elementwise + linear ----------------
        float yp = 0.0f;
        if (tid < H) {
            const float ig = sh_gB[tid];
            const float fg = sh_gB[H + tid];
            const float gg = sh_gB[2 * H + tid];
            const float og = sh_gB[3 * H + tid];
            c2 = fg * c2 + ig * gg;
            const float h2n = og * ftanh(c2);
            sh_h2[tid] = h2n;                                   // h2_new
            yp = wl * h2n;
        }
        if (tid < 64) {                          // wave 0: reduce 51 terms
            yp += __shfl_down(yp, 32);
            yp += __shfl_down(yp, 16);
            yp += __shfl_down(yp, 8);
            yp += __shfl_down(yp, 4);
            yp += __shfl_down(yp, 2);
            yp += __shfl_down(yp, 1);
            if (tid == 0) orow[t] = yp + blin;
        }
        // no B4: every last-read -> next-write pair on sh_h2/sh_gA/sh_gB is
        // separated by at least one of B1(t+1)/B2(t+1)/B3(t+1).
    }
}

extern "C" void kernel_launch(void* const* d_in, const int* in_sizes, int n_in,
                              void* d_out, int out_size, void* d_ws, size_t ws_size,
                              hipStream_t stream)
{
    const float* input = (const float*)d_in[0];
    const float* W_ih1 = (const float*)d_in[1];
    const float* W_hh1 = (const float*)d_in[2];
    const float* b_ih1 = (const float*)d_in[3];
    const float* b_hh1 = (const float*)d_in[4];
    const float* W_ih2 = (const float*)d_in[5];
    const float* W_hh2 = (const float*)d_in[6];
    const float* b_ih2 = (const float*)d_in[7];
    const float* b_hh2 = (const float*)d_in[8];
    const float* W_lin = (const float*)d_in[9];
    const float* b_lin = (const float*)d_in[10];

    float* out = (float*)d_out;

    hipLaunchKernelGGL(lstm2_kernel, dim3(BATCH), dim3(256), 0, stream,
                       input, W_ih1, W_hh1, b_ih1, b_hh1,
                       W_ih2, W_hh2, b_ih2, b_hh2, W_lin, b_lin,
                       out);
}

// Round 7
// 3230.893 us; speedup vs baseline: 1.3828x; 1.0962x over previous
//
#include <hip/hip_runtime.h>

// ---------------------------------------------------------------------------
// 2-layer LSTM (H=51) + Linear(51,1), B=1024, T=1024, fp32.
// Design (R7): SPLIT-K. R3-R6 proved the allocator caps this kernel at 128
// VGPRs and spills any 156-reg weight-resident layout (scratch round-trips
// = the stuck ~3.6 ms). So: split each 51-dot across 4 lanes.
//   - 832 threads/block (13 waves). Lane = (row g = tid>>2, chunk = tid&3);
//     chunk covers h[16*chunk .. +15] (h zero-padded to 64). Per-lane weights:
//     3 matrices x 8 f2 = 48 VGPRs -> fits a 128-reg budget, no spill.
//   - 2 batch elements per block (weights batch-shared: zero extra weight
//     regs, 2x ILP). 512 blocks.
//   - partial dots reduced across the quad via 2x __shfl_xor; gates -> LDS.
//   - c/h elementwise on lanes tid<102 (unit u, batch cb); h via LDS.
//   - y = W_lin.h2 reduced by 16 spare lanes (tid 816..831), DEFERRED one
//     step (read sh_y after B1 of t+1) -> fully overlapped; epilogue for last.
//   - 3 barriers/step; all last-read->next-write LDS pairs barrier-separated.
//   - packed fp32 (v_pk_fma_f32) throughout; fast activations (__expf+rcp).
// ---------------------------------------------------------------------------

#define H    51
#define NG   204      // 4*H
#define TLEN 1024
#define BPB  2        // batch elements per block
#define NTHR 832      // 13 waves: 816 dot lanes + 16 spare
#define NBLK (1024 / BPB)

typedef __attribute__((ext_vector_type(2))) float f2;

__device__ __forceinline__ float frcp(float x) { return __builtin_amdgcn_rcpf(x); }
__device__ __forceinline__ float gate_act(float p, float sm, float am, float bm) {
    return am * frcp(1.0f + __expf(sm * p)) + bm;     // sigmoid/tanh family
}
__device__ __forceinline__ float ftanh(float x) {
    return 1.0f - 2.0f * frcp(__expf(2.0f * x) + 1.0f);
}

__global__
__attribute__((amdgpu_flat_work_group_size(NTHR, NTHR), amdgpu_waves_per_eu(1, 4)))
void lstm2_kernel(const float* __restrict__ input,
                  const float* __restrict__ W_ih1, const float* __restrict__ W_hh1,
                  const float* __restrict__ b_ih1, const float* __restrict__ b_hh1,
                  const float* __restrict__ W_ih2, const float* __restrict__ W_hh2,
                  const float* __restrict__ b_ih2, const float* __restrict__ b_hh2,
                  const float* __restrict__ W_lin, const float* __restrict__ b_lin,
                  float* __restrict__ out)
{
    const int tid = threadIdx.x;
    const int b0  = blockIdx.x * BPB;
    const int row = tid >> 2;          // gate row 0..203 (spares: 204..207)
    const int ch  = tid & 3;           // K-chunk 0..3
    const int cs  = ch * 16;           // chunk start in padded-64 h
    const bool dotlane = tid < 4 * NG; // 816 dot lanes

    __shared__ __align__(16) float sh_h1[BPB][64];   // h1, zero-padded
    __shared__ __align__(16) float sh_h2[BPB][64];   // h2, zero-padded
    __shared__ __align__(16) float sh_y [BPB][64];   // y partials, padded
    __shared__ float sh_gA[BPB][NG];                 // layer-1 gates
    __shared__ float sh_gB[BPB][NG];                 // layer-2 gates

    for (int i = tid; i < BPB * 64; i += NTHR) {
        sh_h1[0][i] = 0.0f; sh_h2[0][i] = 0.0f; sh_y[0][i] = 0.0f;
    }

    // per-lane weight chunk: 8 f2 per matrix, zero-padded beyond element 50
    f2 w1[8], wi2[8], wh2[8];
#pragma unroll
    for (int k = 0; k < 8; ++k) {
        const int e0 = cs + 2 * k, e1 = e0 + 1;
        const bool v0 = dotlane && (e0 < H), v1 = dotlane && (e1 < H);
        w1[k]  = f2{v0 ? W_hh1[row * H + e0] : 0.0f, v1 ? W_hh1[row * H + e1] : 0.0f};
        wi2[k] = f2{v0 ? W_ih2[row * H + e0] : 0.0f, v1 ? W_ih2[row * H + e1] : 0.0f};
        wh2[k] = f2{v0 ? W_hh2[row * H + e0] : 0.0f, v1 ? W_hh2[row * H + e1] : 0.0f};
    }
#pragma unroll
    for (int k = 0; k < 8; ++k) {      // keep non-rematerializable
        asm volatile("" : "+v"(w1[k]), "+v"(wi2[k]), "+v"(wh2[k]));
    }

    const float wx  = dotlane ? W_ih1[row] : 0.0f;
    const float bb1 = dotlane ? (b_ih1[row] + b_hh1[row]) : 0.0f;
    const float bb2 = dotlane ? (b_ih2[row] + b_hh2[row]) : 0.0f;

    const bool  tg = (row >= 2 * H) && (row < 3 * H);   // tanh gate rows
    const float sm = tg ? -2.0f : -1.0f;
    const float am = tg ?  2.0f :  1.0f;
    const float bm = tg ? -1.0f :  0.0f;

    const bool clane = tid < BPB * H;                   // c/h-update lanes
    const int  cb = clane ? (tid / H) : 0;
    const int  cu = clane ? (tid - cb * H) : 0;
    const float wl = clane ? W_lin[cu] : 0.0f;
    const float blin = b_lin[0];
    float c1 = 0.0f, c2 = 0.0f;

    const bool spare = (tid >= 4 * NG) && (tid < 4 * NG + 4 * BPB);
    const int  s  = tid - 4 * NG;
    const int  sb = (s >> 2) & (BPB - 1);
    const int  sp = s & 3;

    __syncthreads();                                    // zeros visible

    for (int t = 0; t < TLEN; ++t) {
        const float x0 = input[(size_t)(b0 + 0) * TLEN + t];   // uniform
        const float x1 = input[(size_t)(b0 + 1) * TLEN + t];

        // ---------------- phase A: layer-1 gate partials ----------------
        {
            const f2* h0 = (const f2*)(&sh_h1[0][cs]);
            const f2* h1 = (const f2*)(&sh_h1[1][cs]);
            f2 p0a = f2{0,0}, p0b = f2{0,0}, p1a = f2{0,0}, p1b = f2{0,0};
#pragma unroll
            for (int k = 0; k < 8; k += 2) {
                p0a = w1[k]   * h0[k]   + p0a;
                p0b = w1[k+1] * h0[k+1] + p0b;
                p1a = w1[k]   * h1[k]   + p1a;
                p1b = w1[k+1] * h1[k+1] + p1b;
            }
            float pr0 = (p0a.x + p0a.y) + (p0b.x + p0b.y);
            float pr1 = (p1a.x + p1a.y) + (p1b.x + p1b.y);
            pr0 += __shfl_xor(pr0, 1);  pr0 += __shfl_xor(pr0, 2);
            pr1 += __shfl_xor(pr1, 1);  pr1 += __shfl_xor(pr1, 2);
            pr0 += bb1 + wx * x0;
            pr1 += bb1 + wx * x1;
            if (dotlane && ch == 0) {
                sh_gA[0][row] = gate_act(pr0, sm, am, bm);
                sh_gA[1][row] = gate_act(pr1, sm, am, bm);
            }
        }
        __syncthreads();                                        // B1

        // ------- phase B: deferred y(t-1) (spares) + layer-1 c/h -------
        if (spare && t > 0) {
            float acc = 0.0f;
#pragma unroll
            for (int j = 0; j < 13; ++j) acc += sh_y[sb][sp * 13 + j];
            acc += __shfl_xor(acc, 1);  acc += __shfl_xor(acc, 2);
            if (sp == 0) out[(size_t)(b0 + sb) * TLEN + (t - 1)] = acc + blin;
        }
        if (clane) {
            const float ig = sh_gA[cb][cu];
            const float fg = sh_gA[cb][H + cu];
            const float gg = sh_gA[cb][2 * H + cu];
            const float og = sh_gA[cb][3 * H + cu];
            c1 = fg * c1 + ig * gg;
            sh_h1[cb][cu] = og * ftanh(c1);
        }
        __syncthreads();                                        // B2

        // ---------------- phase C: layer-2 gate partials ----------------
        {
            const f2* a0p = (const f2*)(&sh_h1[0][cs]);
            const f2* a1p = (const f2*)(&sh_h1[1][cs]);
            const f2* b0p = (const f2*)(&sh_h2[0][cs]);
            const f2* b1p = (const f2*)(&sh_h2[1][cs]);
            f2 p0a = f2{0,0}, p0b = f2{0,0}, p1a = f2{0,0}, p1b = f2{0,0};
#pragma unroll
            for (int k = 0; k < 8; k += 2) {
                p0a = wi2[k]   * a0p[k]   + p0a;
                p0b = wi2[k+1] * a0p[k+1] + p0b;
                p1a = wi2[k]   * a1p[k]   + p1a;
                p1b = wi2[k+1] * a1p[k+1] + p1b;
                p0a = wh2[k]   * b0p[k]   + p0a;
                p0b = wh2[k+1] * b0p[k+1] + p0b;
                p1a = wh2[k]   * b1p[k]   + p1a;
                p1b = wh2[k+1] * b1p[k+1] + p1b;
            }
            float pr0 = (p0a.x + p0a.y) + (p0b.x + p0b.y);
            float pr1 = (p1a.x + p1a.y) + (p1b.x + p1b.y);
            pr0 += __shfl_xor(pr0, 1);  pr0 += __shfl_xor(pr0, 2);
            pr1 += __shfl_xor(pr1, 1);  pr1 += __shfl_xor(pr1, 2);
            pr0 += bb2;
            pr1 += bb2;
            if (dotlane && ch == 0) {
                sh_gB[0][row] = gate_act(pr0, sm, am, bm);
                sh_gB[1][row] = gate_act(pr1, sm, am, bm);
            }
        }
        __syncthreads();                                        // B3

        // ------------- phase D: layer-2 c/h + y partials ---------------
        if (clane) {
            const float ig = sh_gB[cb][cu];
            const float fg = sh_gB[cb][H + cu];
            const float gg = sh_gB[cb][2 * H + cu];
            const float og = sh_gB[cb][3 * H + cu];
            c2 = fg * c2 + ig * gg;
            const float h2n = og * ftanh(c2);
            sh_h2[cb][cu] = h2n;
            sh_y[cb][cu]  = wl * h2n;
        }
        // no barrier: phase A(t+1) touches neither sh_h2/sh_y/sh_gB;
        // first conflicting access is behind B1(t+1)/B2(t+1)/B3(t+1).
    }

    // epilogue: y for t = TLEN-1
    __syncthreads();
    if (spare) {
        float acc = 0.0f;
#pragma unroll
        for (int j = 0; j < 13; ++j) acc += sh_y[sb][sp * 13 + j];
        acc += __shfl_xor(acc, 1);  acc += __shfl_xor(acc, 2);
        if (sp == 0) out[(size_t)(b0 + sb) * TLEN + (TLEN - 1)] = acc + blin;
    }
}

extern "C" void kernel_launch(void* const* d_in, const int* in_sizes, int n_in,
                              void* d_out, int out_size, void* d_ws, size_t ws_size,
                              hipStream_t stream)
{
    const float* input = (const float*)d_in[0];
    const float* W_ih1 = (const float*)d_in[1];
    const float* W_hh1 = (const float*)d_in[2];
    const float* b_ih1 = (const float*)d_in[3];
    const float* b_hh1 = (const float*)d_in[4];
    const float* W_ih2 = (const float*)d_in[5];
    const float* W_hh2 = (const float*)d_in[6];
    const float* b_ih2 = (const float*)d_in[7];
    const float* b_hh2 = (const float*)d_in[8];
    const float* W_lin = (const float*)d_in[9];
    const float* b_lin = (const float*)d_in[10];

    float* out = (float*)d_out;

    hipLaunchKernelGGL(lstm2_kernel, dim3(NBLK), dim3(NTHR), 0, stream,
                       input, W_ih1, W_hh1, b_ih1, b_hh1,
                       W_ih2, W_hh2, b_ih2, b_hh2, W_lin, b_lin,
                       out);
}